// Round 14
// baseline (220.462 us; speedup 1.0000x reference)
//
#include <hip/hip_runtime.h>
#include <hip/hip_bf16.h>

#define N_POINTS   2000000
#define NUM_GRAPHS 16384
#define HID        40
#define SLOPE      0.01f

// Pass A tiling: 256 pts/block, 1 pt/thread (R5-proven)
#define TILE_A     256
#define NT_A       ((N_POINTS + TILE_A - 1) / TILE_A)   // 7813
#define XESA       288    // dwords per xeT channel row

// Pass C tiling: 256 pts/tile, grid-stride, wave-private regions, half-tile xoT.
// R14: R13's half-tile layout + the WAR fix — __syncthreads() after EACH round's
// scan (T0 S0 B T1 S1 B). R13 failed correctness (absmax 9.5): round-0 scan reads
// vs round-1 transpose writes (WAR on the reused half-buffer) got reordered; the
// in-wave-ordering idiom is only proven for the R5 edges (MFMA->T, T->S), NOT for
// buffer-reuse WAR. LDS 38.4->23.6 KB -> 6 blocks/CU; grid 1536 exactly resident.
#define TILE       256
#define NTILES     ((N_POINTS + TILE - 1) / TILE)       // 7813
#define AROW       20     // dwords per bf16 A-staging row (40 bf16)
#define XOSH       36     // half-tile xoT stride: [ch][32 pts + 4 pad]
#define WREG       (64 * AROW)   // 1280 dwords = 5120 B per-wave region (xoT_half aliases)
#define NB_C       1536   // 6 blocks/CU x 256 CU, exactly resident

// LEDGER (cross-round, do not relearn):
//  - PHANTOM-TRAFFIC DISEASE (R1,R3,R6,R7,R9,R10): per-graph variable-trip nested
//    outer loops -> GB-scale scratch-like FETCH/WRITE. Flat grid-stride is clean.
//    DO NOT reintroduce. CANARY: WRITE_SIZE >> real stores.
//  - R2: pooled atomics need temporally-clustered reduce phases (barrier) or L2
//    write-combining dies. R11: oversubscribed grid also hurts combining.
//  - R13: in-wave DS ordering does NOT cover buffer-reuse WAR edges (scan-read ->
//    re-write). Any new dependence edge on reused LDS needs an explicit barrier.
//  - R4: batch/xe reg prefetch neutral. R12: pass A grid-stride neutral/-5us.
//  - R5 champion: 189.7us; k_out_pool 61.4us / VGPR 64 / WRITE 20.9MB / LDS 38.4KB
//    / Occupancy 38% (4 blocks/CU, LDS-capped). R14 attacks occupancy via LDS.

typedef __attribute__((ext_vector_type(8))) short short8;
typedef __attribute__((ext_vector_type(4))) float fx4;

__device__ __forceinline__ float lrelu(float v) { return v > 0.f ? v : SLOPE * v; }
__device__ __forceinline__ int padidx(int p) { return p + ((p >> 5) << 2); }  // +4 dwords per 32-chunk
__device__ __forceinline__ unsigned short f2bf(float f) {
    __hip_bfloat16 h = __float2bfloat16(f);
    return *(unsigned short*)&h;
}
__device__ __forceinline__ float bf2f(unsigned short u) {
    unsigned int v = ((unsigned int)u) << 16;
    return __uint_as_float(v);
}

// ---------------- Pass A: emb FFN (1 pt/thread, h[40]/j4 body) + transpose-reduce + xe cache ----------------
// R5-proven verbatim (7813 blocks, one tile each).
__global__ __launch_bounds__(256, 4) void k_emb_aggr(
    const float* __restrict__ x, const int* __restrict__ batch,
    const float* __restrict__ We1, const float* __restrict__ We2,
    float* __restrict__ x_aggr, unsigned short* __restrict__ xe_out, int use_xe)
{
    __shared__ __align__(16) float sWe1[3 * HID];
    __shared__ __align__(16) float sWe2T[5 * HID];          // [c][j]
    __shared__ __align__(16) float xeT[5 * XESA];           // chunk-padded
    __shared__ __align__(16) int   sbp[XESA];

    int tid = threadIdx.x;
    for (int k = tid; k < 3 * HID; k += 256) sWe1[k] = We1[k];
    for (int k = tid; k < 5 * HID; k += 256) sWe2T[k] = We2[(k % HID) * 5 + k / HID];
    __syncthreads();

    int p = blockIdx.x * TILE_A + tid;
    bool v = p < N_POINTS;
    int ic = v ? p : (N_POINTS - 1);
    float x0 = x[ic * 3 + 0], x1 = x[ic * 3 + 1], x2 = x[ic * 3 + 2];
    int b = v ? batch[ic] : -1;
    sbp[padidx(tid)] = b;

    float h[HID];
    const float4* W1r = (const float4*)sWe1;
#pragma unroll
    for (int j4 = 0; j4 < HID / 4; ++j4) {
        float4 wa = W1r[j4], wb = W1r[10 + j4], wc = W1r[20 + j4];
        float wav[4] = {wa.x, wa.y, wa.z, wa.w};
        float wbv[4] = {wb.x, wb.y, wb.z, wb.w};
        float wcv[4] = {wc.x, wc.y, wc.z, wc.w};
#pragma unroll
        for (int k = 0; k < 4; ++k)
            h[j4 * 4 + k] = lrelu(x0 * wav[k] + x1 * wbv[k] + x2 * wcv[k]);
    }

#pragma unroll
    for (int c = 0; c < 5; ++c) {
        const float4* wr = (const float4*)&sWe2T[c * HID];
        float s = 0.f;
#pragma unroll
        for (int j4 = 0; j4 < HID / 4; ++j4) {
            float4 w = wr[j4];
            s += h[j4 * 4 + 0] * w.x + h[j4 * 4 + 1] * w.y + h[j4 * 4 + 2] * w.z + h[j4 * 4 + 3] * w.w;
        }
        float e = v ? lrelu(s) : 0.f;
        xeT[c * XESA + padidx(tid)] = e;
        if (use_xe && v) xe_out[(size_t)c * N_POINTS + p] = f2bf(e);
    }
    __syncthreads();

    if (tid < 40) {
        int ch = tid >> 3, chunk = tid & 7;
        float acc = 0.f;
        int cur = sbp[chunk * 36];
#pragma unroll
        for (int g = 0; g < 8; ++g) {
            float4 v4 = *(const float4*)&xeT[ch * XESA + chunk * 36 + g * 4];
            int4   n4 = *(const int4*)&sbp[chunk * 36 + g * 4];
            float vv[4] = {v4.x, v4.y, v4.z, v4.w};
            int   nn[4] = {n4.x, n4.y, n4.z, n4.w};
#pragma unroll
            for (int k = 0; k < 4; ++k) {
                if (nn[k] != cur) {
                    if (cur >= 0) atomicAdd(&x_aggr[cur * 5 + ch], acc);
                    cur = nn[k];
                    acc = vv[k];
                } else {
                    acc += vv[k];
                }
            }
        }
        if (cur >= 0) atomicAdd(&x_aggr[cur * 5 + ch], acc);
    }
}

// ---------------- Pass B: per-graph global FFN + fold into W_out1 rows 5..8 ----------------
__global__ __launch_bounds__(256) void k_global(
    const float* __restrict__ x_aggr,
    const float* __restrict__ Wg1, const float* __restrict__ Wg2,
    const float* __restrict__ Wo1,
    float* __restrict__ g_contrib)
{
    __shared__ float sWg1[5 * HID];
    __shared__ float sWg2[HID * 4];
    __shared__ float sWo1g[4 * HID];
    for (int k = threadIdx.x; k < 5 * HID; k += 256) sWg1[k] = Wg1[k];
    for (int k = threadIdx.x; k < HID * 4; k += 256) sWg2[k] = Wg2[k];
    for (int k = threadIdx.x; k < 4 * HID; k += 256) sWo1g[k] = Wo1[5 * HID + k];
    __syncthreads();

    int bg = blockIdx.x * 256 + threadIdx.x;
    if (bg >= NUM_GRAPHS) return;

    float a[5];
#pragma unroll
    for (int c = 0; c < 5; ++c) a[c] = x_aggr[bg * 5 + c];

    float h[HID];
#pragma unroll
    for (int j = 0; j < HID; ++j) {
        float s = 0.f;
#pragma unroll
        for (int c = 0; c < 5; ++c) s += a[c] * sWg1[c * HID + j];
        h[j] = lrelu(s);
    }
    float g[4];
#pragma unroll
    for (int c = 0; c < 4; ++c) {
        float s = 0.f;
#pragma unroll
        for (int j = 0; j < HID; ++j) s += h[j] * sWg2[j * 4 + c];
        g[c] = lrelu(s);
    }
#pragma unroll
    for (int j = 0; j < HID; ++j) {
        float s = 0.f;
#pragma unroll
        for (int c = 0; c < 4; ++c) s += g[c] * sWo1g[c * HID + j];
        g_contrib[bg * HID + j] = s;
    }
}

// ---------------- Pass C: wave-private regions, half-tile xoT, barrier per round ----------------
// Per tile: stage h1 -> MFMA all 4 m-tiles into regs -> 2x { transpose 2 m-tiles
// into 32x36 half-buffer -> lanes 0-31 run-length scan -> __syncthreads() }.
// The barrier after each scan closes the R13 WAR (scan reads vs next round's
// writes) and the second one doubles as the tile-end rate-matcher (R2 lesson).
__global__ __launch_bounds__(256, 4) void k_out_pool(
    const float* __restrict__ x, const int* __restrict__ batch,
    const float* __restrict__ We1, const float* __restrict__ We2,
    const float* __restrict__ Wo1, const float* __restrict__ Wo2,
    const float* __restrict__ g_contrib,
    const unsigned short* __restrict__ xe_in, int use_xe,
    float* __restrict__ pooled)
{
    __shared__ __align__(16) unsigned int uLds[4 * WREG];   // 20480 B total
    __shared__ __align__(16) int sb[TILE];
    __shared__ float sWe1[3 * HID];
    __shared__ float sWe2T[5 * HID];
    __shared__ float sWo1[5 * HID];

    int tid = threadIdx.x;
    for (int k = tid; k < 3 * HID; k += 256) sWe1[k] = We1[k];
    for (int k = tid; k < 5 * HID; k += 256) sWe2T[k] = We2[(k % HID) * 5 + k / HID];
    for (int k = tid; k < 5 * HID; k += 256) sWo1[k] = Wo1[k];

    int wid = tid >> 6, lane = tid & 63;
    int l16 = lane & 15, quad = lane >> 4;
    unsigned int* wreg = &uLds[wid * WREG];

    short8 bfrag[2][2];
#pragma unroll
    for (int nt = 0; nt < 2; ++nt) {
#pragma unroll
        for (int ks = 0; ks < 2; ++ks) {
#pragma unroll
            for (int j = 0; j < 8; ++j) {
                int kk = ks * 32 + quad * 8 + j;
                float w = (kk < HID) ? Wo2[kk * 32 + nt * 16 + l16] : 0.f;
                bfrag[nt][ks][j] = (short)f2bf(w);
            }
        }
    }
    short8 zfrag = {0, 0, 0, 0, 0, 0, 0, 0};
    __syncthreads();   // weights visible

    for (int t = blockIdx.x; t < NTILES; t += gridDim.x) {
        int i = t * TILE + tid;
        bool v = i < N_POINTS;
        int ic = v ? i : (N_POINTS - 1);
        int b = v ? batch[ic] : -1;
        sb[tid] = b;    // wave-private slice: only own wave reads sb[wid*64..+63]

        float xe[5];
        if (use_xe) {
#pragma unroll
            for (int c = 0; c < 5; ++c) xe[c] = bf2f(xe_in[(size_t)c * N_POINTS + ic]);
        } else {
            float x0 = x[ic * 3 + 0], x1 = x[ic * 3 + 1], x2 = x[ic * 3 + 2];
            float h[HID];
            const float4* W1r = (const float4*)sWe1;
#pragma unroll
            for (int j4 = 0; j4 < HID / 4; ++j4) {
                float4 wa = W1r[j4], wb = W1r[10 + j4], wc = W1r[20 + j4];
                float wav[4] = {wa.x, wa.y, wa.z, wa.w};
                float wbv[4] = {wb.x, wb.y, wb.z, wb.w};
                float wcv[4] = {wc.x, wc.y, wc.z, wc.w};
#pragma unroll
                for (int k = 0; k < 4; ++k)
                    h[j4 * 4 + k] = lrelu(x0 * wav[k] + x1 * wbv[k] + x2 * wcv[k]);
            }
#pragma unroll
            for (int c = 0; c < 5; ++c) {
                const float4* wr = (const float4*)&sWe2T[c * HID];
                float s = 0.f;
#pragma unroll
                for (int j4 = 0; j4 < HID / 4; ++j4) {
                    float4 w = wr[j4];
                    s += h[j4 * 4 + 0] * w.x + h[j4 * 4 + 1] * w.y + h[j4 * 4 + 2] * w.z + h[j4 * 4 + 3] * w.w;
                }
                xe[c] = lrelu(s);
            }
        }

        // h1 = lrelu(xe @ Wo1[0:5] + g_contrib[b]); pack bf16; stage A row (wave-private)
        const float4* gc4 = (const float4*)(g_contrib + (size_t)(b >= 0 ? b : 0) * HID);
        unsigned int* row = &wreg[lane * AROW];
#pragma unroll
        for (int j4 = 0; j4 < HID / 4; ++j4) {
            float4 g = gc4[j4];
            float sv[4] = {g.x, g.y, g.z, g.w};
#pragma unroll
            for (int c = 0; c < 5; ++c) {
                float4 w = ((const float4*)&sWo1[c * HID])[j4];
                float wvv[4] = {w.x, w.y, w.z, w.w};
#pragma unroll
                for (int k = 0; k < 4; ++k) sv[k] += xe[c] * wvv[k];
            }
            __hip_bfloat162 q0 = __float22bfloat162_rn(make_float2(lrelu(sv[0]), lrelu(sv[1])));
            __hip_bfloat162 q1 = __float22bfloat162_rn(make_float2(lrelu(sv[2]), lrelu(sv[3])));
            uint2 u;
            u.x = *(unsigned int*)&q0; u.y = *(unsigned int*)&q1;
            *(uint2*)(row + j4 * 2) = u;
        }

        // MFMA all 4 m-tiles x 2 ntiles into registers; K = 32 + 8
        fx4 xov[4][2];
#pragma unroll
        for (int m = 0; m < 4; ++m) {
            const unsigned int* arow = &wreg[(m * 16 + l16) * AROW];
            short8 a0 = *(const short8*)(arow + quad * 4);
            short8 a1 = (quad == 0) ? *(const short8*)(arow + 16) : zfrag;
#pragma unroll
            for (int nt = 0; nt < 2; ++nt) {
                fx4 acc = {0.f, 0.f, 0.f, 0.f};
                acc = __builtin_amdgcn_mfma_f32_16x16x32_bf16(a0, bfrag[nt][0], acc, 0, 0, 0);
                acc = __builtin_amdgcn_mfma_f32_16x16x32_bf16(a1, bfrag[nt][1], acc, 0, 0, 0);
#pragma unroll
                for (int r = 0; r < 4; ++r) acc[r] = lrelu(acc[r]);
                xov[m][nt] = acc;
            }
        }

        // 2 rounds: transpose 2 m-tiles (32 pts) into half-buffer, scan, BARRIER.
        // (MFMA reads -> transpose writes: in-wave RAW/WAR on own region, R5-proven.
        //  scan reads -> next round's writes: WAR closed by the barrier — R13 lesson.)
        float* xoT = (float*)wreg;
#pragma unroll
        for (int r2 = 0; r2 < 2; ++r2) {
#pragma unroll
            for (int mm = 0; mm < 2; ++mm) {
#pragma unroll
                for (int nt = 0; nt < 2; ++nt) {
                    int ch = nt * 16 + l16;
                    *(fx4*)&xoT[ch * XOSH + mm * 16 + quad * 4] = xov[r2 * 2 + mm][nt];
                }
            }
            if (lane < 32) {
                int ch = lane;
                const int* sbw = &sb[wid * 64 + r2 * 32];
                float acc = 0.f;
                int cur = sbw[0];
#pragma unroll
                for (int g = 0; g < 8; ++g) {
                    float4 v4 = *(const float4*)&xoT[ch * XOSH + g * 4];
                    int4   n4 = *(const int4*)&sbw[g * 4];
                    float vv[4] = {v4.x, v4.y, v4.z, v4.w};
                    int   nn[4] = {n4.x, n4.y, n4.z, n4.w};
#pragma unroll
                    for (int k = 0; k < 4; ++k) {
                        if (nn[k] != cur) {
                            if (cur >= 0) atomicAdd(&pooled[cur * 32 + ch], acc);
                            cur = nn[k];
                            acc = vv[k];
                        } else {
                            acc += vv[k];
                        }
                    }
                }
                if (cur >= 0) atomicAdd(&pooled[cur * 32 + ch], acc);
            }
            __syncthreads();   // close WAR on half-buffer; 2nd iter = tile rate-match
        }
    }
}

// ---------------- Pass D: disc head per graph ----------------
__global__ __launch_bounds__(256) void k_disc(
    const float* __restrict__ pooled,
    const float* __restrict__ Wd1, const float* __restrict__ Wd2,
    float* __restrict__ out)
{
    __shared__ float sWd1T[HID * 32];  // [j][c]
    __shared__ float sWd2[HID];
    for (int k = threadIdx.x; k < 32 * HID; k += 256) sWd1T[k] = Wd1[(k % 32) * HID + k / 32];
    for (int k = threadIdx.x; k < HID; k += 256) sWd2[k] = Wd2[k];
    __syncthreads();

    int bg = blockIdx.x * 256 + threadIdx.x;
    if (bg >= NUM_GRAPHS) return;

    float p[32];
    const float4* pp = (const float4*)(pooled + (size_t)bg * 32);
#pragma unroll
    for (int c4 = 0; c4 < 8; ++c4) {
        float4 vv = pp[c4];
        p[c4 * 4 + 0] = vv.x; p[c4 * 4 + 1] = vv.y; p[c4 * 4 + 2] = vv.z; p[c4 * 4 + 3] = vv.w;
    }

    float acc = 0.f;
#pragma unroll
    for (int j = 0; j < HID; ++j) {
        const float4* wr = (const float4*)&sWd1T[j * 32];
        float s = 0.f;
#pragma unroll
        for (int c4 = 0; c4 < 8; ++c4) {
            float4 w = wr[c4];
            s += p[c4 * 4 + 0] * w.x + p[c4 * 4 + 1] * w.y + p[c4 * 4 + 2] * w.z + p[c4 * 4 + 3] * w.w;
        }
        acc += lrelu(s) * sWd2[j];
    }
    out[bg] = acc;
}

extern "C" void kernel_launch(void* const* d_in, const int* in_sizes, int n_in,
                              void* d_out, int out_size, void* d_ws, size_t ws_size,
                              hipStream_t stream) {
    const float* x     = (const float*)d_in[0];
    const int*   batch = (const int*)  d_in[1];
    const float* We1   = (const float*)d_in[2];
    const float* We2   = (const float*)d_in[3];
    const float* Wg1   = (const float*)d_in[4];
    const float* Wg2   = (const float*)d_in[5];
    const float* Wo1   = (const float*)d_in[6];
    const float* Wo2   = (const float*)d_in[7];
    const float* Wd1   = (const float*)d_in[8];
    const float* Wd2   = (const float*)d_in[9];
    float* out = (float*)d_out;

    // ws layout: [x_aggr B*5][pooled B*32][g_contrib B*40][xe bf16 planar 5*N]
    float* x_aggr    = (float*)d_ws;
    float* pooled    = x_aggr + NUM_GRAPHS * 5;
    float* g_contrib = pooled + NUM_GRAPHS * 32;
    size_t head_bytes = (size_t)NUM_GRAPHS * (5 + 32 + HID) * sizeof(float);
    unsigned short* xe_ws = (unsigned short*)((char*)d_ws + head_bytes);
    size_t need = head_bytes + (size_t)N_POINTS * 5 * sizeof(unsigned short);
    int use_xe = (ws_size >= need) ? 1 : 0;

    hipMemsetAsync(d_ws, 0, (size_t)NUM_GRAPHS * (5 + 32) * sizeof(float), stream);

    int gblk = (NUM_GRAPHS + 255) / 256;
    k_emb_aggr<<<NT_A, 256, 0, stream>>>(x, batch, We1, We2, x_aggr, xe_ws, use_xe);
    k_global <<<gblk, 256, 0, stream>>>(x_aggr, Wg1, Wg2, Wo1, g_contrib);
    k_out_pool<<<NB_C, 256, 0, stream>>>(x, batch, We1, We2, Wo1, Wo2, g_contrib,
                                         xe_ws, use_xe, pooled);
    k_disc   <<<gblk, 256, 0, stream>>>(pooled, Wd1, Wd2, out);
}